// Round 1
// baseline (164.732 us; speedup 1.0000x reference)
//
#include <hip/hip_runtime.h>
#include <stdint.h>

// Problem constants
#define NBATCH 1024
#define NQ 300
#define NC 80
#define QC 24000      // NQ * NC
#define TOPK 300
#define NT 512        // threads per block
#define SELCAP 1024   // max collected candidates (>= TOPK + slack for ties)

// Shared memory layout (uint32 units)
#define OFF_HIST 24000          // 4096 buckets
#define OFF_SEL  28096          // 1024 x u64 = 2048 u32 (8B aligned: 28096*4 % 8 == 0)
#define OFF_PART 30144          // 512 scan partials
#define OFF_MISC 30656          // small scratch
#define SMEM_U32 30672          // total: 122,688 bytes

__device__ __forceinline__ uint32_t sig_bits(float x) {
    // accurate f32 sigmoid; positive value -> bit pattern is order-preserving
    float s = 1.0f / (1.0f + expf(-x));
    return __float_as_uint(s);
}

// Given hist[nb], find the bucket (counting from the highest) containing the
// rem_in-th largest element; return bucket and the residual count inside it.
__device__ void pick_bucket(uint32_t* __restrict__ hist, uint32_t* __restrict__ part,
                            uint32_t* __restrict__ misc, int nb, int tid,
                            uint32_t rem_in, uint32_t* bucket_out, uint32_t* rem_out) {
    int g = nb / NT; if (g == 0) g = 1;
    int base = tid * g;
    uint32_t sum = 0;
    if (base < nb) {
        for (int u = 0; u < g; ++u) sum += hist[base + u];
    }
    part[tid] = sum;
    __syncthreads();
    // inclusive suffix scan (Hillis-Steele): part[t] = count of buckets >= t*g
    for (int off = 1; off < NT; off <<= 1) {
        uint32_t v = part[tid];
        if (tid + off < NT) v += part[tid + off];
        __syncthreads();
        part[tid] = v;
        __syncthreads();
    }
    uint32_t S  = part[tid];
    uint32_t Sn = (tid + 1 < NT) ? part[tid + 1] : 0u;
    if (base < nb && S >= rem_in && Sn < rem_in) {   // unique boundary group
        uint32_t r = rem_in - Sn;                    // needed within this group
        uint32_t acc = 0;
        uint32_t bsel = base;
        for (int u = g - 1; u >= 0; --u) {           // walk group's buckets, high->low
            uint32_t h = hist[base + u];
            if (acc + h >= r) { bsel = base + u; r -= acc; break; }
            acc += h;
        }
        misc[0] = bsel; misc[1] = r;
    }
    __syncthreads();
    *bucket_out = misc[0];
    *rem_out    = misc[1];
    __syncthreads();
}

__global__ void __launch_bounds__(NT, 1)
rtdetr_post_kernel(const float* __restrict__ logits, const float* __restrict__ pboxes,
                   const float* __restrict__ sizes, float* __restrict__ out) {
    extern __shared__ uint32_t sm[];
    uint32_t* sdata = sm;                                    // 24000 score bit patterns
    uint32_t* hist  = sm + OFF_HIST;                         // 4096
    uint64_t* sel   = reinterpret_cast<uint64_t*>(sm + OFF_SEL); // 1024 u64
    uint32_t* part  = sm + OFF_PART;                         // 512
    uint32_t* misc  = sm + OFF_MISC;

    const int tid = threadIdx.x;
    const int b   = blockIdx.x;

    // ---- Phase 1: load logits (float4) + sigmoid -> LDS ----
    const float4* lg4 = reinterpret_cast<const float4*>(logits + (size_t)b * QC);
    for (int i = tid; i < QC / 4; i += NT) {
        float4 v = lg4[i];
        sdata[i * 4 + 0] = sig_bits(v.x);
        sdata[i * 4 + 1] = sig_bits(v.y);
        sdata[i * 4 + 2] = sig_bits(v.z);
        sdata[i * 4 + 3] = sig_bits(v.w);
    }
    for (int i = tid; i < 4096; i += NT) hist[i] = 0;
    __syncthreads();

    // ---- Phase 2: radix select, pass A: bits[31:20] ----
    for (int i = tid; i < QC; i += NT) {
        atomicAdd(&hist[sdata[i] >> 20], 1u);
    }
    __syncthreads();
    uint32_t b1, r1;
    pick_bucket(hist, part, misc, 4096, tid, (uint32_t)TOPK, &b1, &r1);

    // ---- pass B: bits[19:8] among prefix matches ----
    for (int i = tid; i < 4096; i += NT) hist[i] = 0;
    __syncthreads();
    for (int i = tid; i < QC; i += NT) {
        uint32_t v = sdata[i];
        if ((v >> 20) == b1) atomicAdd(&hist[(v >> 8) & 0xFFFu], 1u);
    }
    __syncthreads();
    uint32_t b2, r2;
    pick_bucket(hist, part, misc, 4096, tid, r1, &b2, &r2);
    const uint32_t p24 = (b1 << 12) | b2;

    // ---- pass C: bits[7:0] among prefix matches ----
    for (int i = tid; i < 256; i += NT) hist[i] = 0;
    __syncthreads();
    for (int i = tid; i < QC; i += NT) {
        uint32_t v = sdata[i];
        if ((v >> 8) == p24) atomicAdd(&hist[v & 0xFFu], 1u);
    }
    __syncthreads();
    uint32_t b3, r3;
    pick_bucket(hist, part, misc, 256, tid, r2, &b3, &r3);
    const uint32_t T = (p24 << 8) | b3;   // exact K-th largest score bits

    // ---- Phase 3: collect all candidates with bits >= T ----
    if (tid == 0) misc[2] = 0;
    __syncthreads();
    for (int i = tid; i < QC; i += NT) {
        uint32_t v = sdata[i];
        if (v >= T) {
            uint32_t pos = atomicAdd(&misc[2], 1u);
            if (pos < SELCAP)
                sel[pos] = ((uint64_t)v << 32) | (uint64_t)(0xFFFFFFFFu - (uint32_t)i);
        }
    }
    __syncthreads();
    uint32_t cnt = misc[2];
    uint32_t n = cnt > SELCAP ? SELCAP : cnt;
    unsigned m = 512; while (m < n) m <<= 1;          // 512 or 1024
    for (unsigned i = n + tid; i < m; i += NT) sel[i] = 0ull;  // pad: sorts last
    __syncthreads();

    // ---- Phase 4: bitonic sort descending by (score_bits, ~idx) ----
    // key ordering gives: score desc, then index asc (matches jax.lax.top_k)
    for (unsigned k = 2; k <= m; k <<= 1) {
        for (unsigned j = k >> 1; j > 0; j >>= 1) {
            for (unsigned i = tid; i < m; i += NT) {
                unsigned ixj = i ^ j;
                if (ixj > i) {
                    uint64_t a = sel[i], c2 = sel[ixj];
                    bool desc = ((i & k) == 0);
                    if (desc ? (a < c2) : (a > c2)) { sel[i] = c2; sel[ixj] = a; }
                }
            }
            __syncthreads();
        }
    }

    // ---- Phase 5: epilogue: labels, boxes (cxcywh->xyxy, scaled), scores ----
    if (tid < TOPK) {
        uint64_t key  = sel[tid];
        uint32_t sbits = (uint32_t)(key >> 32);
        uint32_t idx   = 0xFFFFFFFFu - (uint32_t)(key & 0xFFFFFFFFull);
        uint32_t lab   = idx % NC;
        uint32_t q     = idx / NC;
        const float4* bx4 = reinterpret_cast<const float4*>(pboxes + (size_t)b * NQ * 4);
        float4 bx = bx4[q];
        float sw = sizes[2 * b + 0];
        float sh = sizes[2 * b + 1];
        float hw = 0.5f * bx.z, hh = 0.5f * bx.w;
        float4 o;
        o.x = (bx.x - hw) * sw;
        o.y = (bx.y - hh) * sh;
        o.z = (bx.x + hw) * sw;
        o.w = (bx.y + hh) * sh;
        out[(size_t)b * TOPK + tid] = (float)lab;                                  // labels
        reinterpret_cast<float4*>(out + (size_t)NBATCH * TOPK)[(size_t)b * TOPK + tid] = o; // boxes
        out[(size_t)NBATCH * TOPK * 5 + (size_t)b * TOPK + tid] = __uint_as_float(sbits);   // scores
    }
}

extern "C" void kernel_launch(void* const* d_in, const int* in_sizes, int n_in,
                              void* d_out, int out_size, void* d_ws, size_t ws_size,
                              hipStream_t stream) {
    const float* logits = (const float*)d_in[0];   // [1024,300,80] f32
    const float* pboxes = (const float*)d_in[1];   // [1024,300,4]  f32
    const float* sizes  = (const float*)d_in[2];   // [1024,2]      f32
    float* out = (float*)d_out;                    // labels | boxes | scores (flat f32)

    size_t smem = (size_t)SMEM_U32 * sizeof(uint32_t);   // 122,688 B dynamic LDS
    // Opt in to >64KB dynamic LDS (no-op/harmless if not required on ROCm)
    (void)hipFuncSetAttribute(reinterpret_cast<const void*>(rtdetr_post_kernel),
                              hipFuncAttributeMaxDynamicSharedMemorySize, (int)smem);

    hipLaunchKernelGGL(rtdetr_post_kernel, dim3(NBATCH), dim3(NT), smem, stream,
                       logits, pboxes, sizes, out);
}

// Round 2
// 58.283 us; speedup vs baseline: 2.8264x; 2.8264x over previous
//
#include <hip/hip_runtime.h>
#include <stdint.h>

// Problem constants
#define NBATCH 1024
#define NQ 300
#define NC 80
#define QC 24000      // NQ * NC floats per batch
#define NF4 6000      // QC / 4
#define TOPK 300
#define RSEL 384u     // radix-select target rank (margin over 300 covers sigmoid ties)
#define NT 512        // threads per block
#define SELCAP 512    // candidate buffer
#define NV4 12        // float4 slots per thread (11 full + tail)
#define TAIL4 368     // threads with a valid 12th float4 (6000 - 11*512)

// ---------------------------------------------------------------------------
// pick<NB>: given hist[NB] (finalized), find bucket (from the top) containing
// the rem-th largest element and the residual count inside it. 3 barriers.
// Two-level suffix scan: per-thread sum -> 64 group sums (wave0, shfl scan).
// ---------------------------------------------------------------------------
template<int NB>
__device__ __forceinline__ void pick(const uint32_t* __restrict__ hist,
                                     uint32_t* __restrict__ part,
                                     uint32_t* __restrict__ gsufx,
                                     uint32_t* __restrict__ misc,
                                     int tid, uint32_t rem,
                                     uint32_t* bucket_out, uint32_t* rem_out) {
    constexpr int G = (NB >= NT) ? (NB / NT) : 1;
    const int base = tid * G;
    uint32_t h[G];
    uint32_t s = 0;
    if (base < NB) {
#pragma unroll
        for (int u = 0; u < G; ++u) { h[u] = hist[base + u]; s += h[u]; }
    } else {
#pragma unroll
        for (int u = 0; u < G; ++u) h[u] = 0;
    }
    part[tid] = s;
    __syncthreads();

    if (tid < 64) {
        uint32_t gs = 0;
#pragma unroll
        for (int u = 0; u < 8; ++u) gs += part[(tid << 3) + u];
        // suffix scan across 64 lanes: S_l = sum_{l' >= l} gs_{l'}
        uint32_t S = gs;
#pragma unroll
        for (int off = 1; off < 64; off <<= 1) {
            uint32_t v = __shfl_down(S, off, 64);
            if (tid + off < 64) S += v;
        }
        gsufx[tid] = S;
        if (tid == 0) gsufx[64] = 0;
    }
    __syncthreads();

    const int g8 = tid >> 3;
    uint32_t A = gsufx[g8 + 1];                 // count strictly above this group
    for (int t2 = tid + 1; t2 < ((g8 + 1) << 3); ++t2) A += part[t2];
    // A = count of elements in buckets strictly above this thread's buckets
    if (base < NB && A < rem && A + s >= rem) {
        uint32_t acc = 0, bsel = (uint32_t)base, r = 1;
#pragma unroll
        for (int u = G - 1; u >= 0; --u) {
            if (A + acc + h[u] >= rem) { bsel = (uint32_t)(base + u); r = rem - A - acc; break; }
            acc += h[u];
        }
        misc[0] = bsel;
        misc[1] = r;
    }
    __syncthreads();
    *bucket_out = misc[0];
    *rem_out    = misc[1];
}

__global__ void __launch_bounds__(NT, 4)
rtdetr_post_kernel(const float* __restrict__ logits, const float* __restrict__ pboxes,
                   const float* __restrict__ sizes, float* __restrict__ out) {
    __shared__ uint64_t sel[SELCAP];
    __shared__ uint32_t hist[4096];
    __shared__ uint32_t part[NT];
    __shared__ uint32_t gsufx[65];
    __shared__ uint32_t misc[4];

    const int tid = threadIdx.x;
    const int b   = blockIdx.x;

    // ---- zero hist + candidate counter; issue global loads (overlap) ----
    for (int i = tid; i < 4096; i += NT) hist[i] = 0;
    if (tid == 0) misc[2] = 0;

    // keys: order-preserving u32 transform of logit f32 bits
    uint32_t key[NV4 * 4];
    const float4* lg4 = reinterpret_cast<const float4*>(logits + (size_t)b * QC);
#pragma unroll
    for (int k = 0; k < NV4; ++k) {
        const int i4 = tid + (k << 9);
        if (k < NV4 - 1 || tid < TAIL4) {
            float4 v = lg4[i4];
            uint32_t u0 = __float_as_uint(v.x), u1 = __float_as_uint(v.y);
            uint32_t u2 = __float_as_uint(v.z), u3 = __float_as_uint(v.w);
            key[4 * k + 0] = (u0 & 0x80000000u) ? ~u0 : (u0 | 0x80000000u);
            key[4 * k + 1] = (u1 & 0x80000000u) ? ~u1 : (u1 | 0x80000000u);
            key[4 * k + 2] = (u2 & 0x80000000u) ? ~u2 : (u2 | 0x80000000u);
            key[4 * k + 3] = (u3 & 0x80000000u) ? ~u3 : (u3 | 0x80000000u);
        } else {
            key[4 * k + 0] = 0; key[4 * k + 1] = 0; key[4 * k + 2] = 0; key[4 * k + 3] = 0;
        }
    }
    __syncthreads();

    // ---- pass A: histogram key[31:20] (4096 buckets) ----
#pragma unroll
    for (int k = 0; k < NV4; ++k) {
        if (k < NV4 - 1 || tid < TAIL4) {
#pragma unroll
            for (int c = 0; c < 4; ++c)
                atomicAdd(&hist[key[4 * k + c] >> 20], 1u);
        }
    }
    __syncthreads();
    uint32_t b1, r1;
    pick<4096>(hist, part, gsufx, misc, tid, RSEL, &b1, &r1);

    // ---- pass B: histogram key[19:8] among bucket-b1 matches ----
    for (int i = tid; i < 4096; i += NT) hist[i] = 0;
    __syncthreads();
#pragma unroll
    for (int k = 0; k < NV4; ++k) {
#pragma unroll
        for (int c = 0; c < 4; ++c) {
            uint32_t v = key[4 * k + c];
            if ((v >> 20) == b1) atomicAdd(&hist[(v >> 8) & 0xFFFu], 1u);
        }
    }
    __syncthreads();
    uint32_t b2, r2;
    pick<4096>(hist, part, gsufx, misc, tid, r1, &b2, &r2);
    const uint32_t p24 = (b1 << 12) | b2;

    // ---- pass C: histogram key[7:0] among 24-bit prefix matches ----
    if (tid < 256) hist[tid] = 0;
    __syncthreads();
#pragma unroll
    for (int k = 0; k < NV4; ++k) {
#pragma unroll
        for (int c = 0; c < 4; ++c) {
            uint32_t v = key[4 * k + c];
            if ((v >> 8) == p24) atomicAdd(&hist[v & 0xFFu], 1u);
        }
    }
    __syncthreads();
    uint32_t b3, r3;
    pick<256>(hist, part, gsufx, misc, tid, r2, &b3, &r3);
    (void)r3;
    const uint32_t T = (p24 << 8) | b3;  // exact bits of the rank-RSEL logit key

    // ---- collect all elements with key >= T (n in [RSEL, RSEL+dups]) ----
#pragma unroll
    for (int k = 0; k < NV4; ++k) {
#pragma unroll
        for (int c = 0; c < 4; ++c) {
            uint32_t v = key[4 * k + c];
            if (v >= T) {
                uint32_t pos = atomicAdd(&misc[2], 1u);
                uint32_t idx = 4u * (uint32_t)(tid + (k << 9)) + (uint32_t)c;
                if (pos < SELCAP)
                    sel[pos] = ((uint64_t)v << 32) | (uint64_t)(0xFFFFFFFFu - idx);
            }
        }
    }
    __syncthreads();
    const uint32_t cnt = misc[2];
    const uint32_t n = cnt > SELCAP ? SELCAP : cnt;

    // ---- sigmoid only for candidates; rebuild key as (score_bits, ~idx) ----
    uint64_t mykey = 0;
    if ((uint32_t)tid < n) {
        uint64_t e = sel[tid];
        uint32_t lk = (uint32_t)(e >> 32);
        uint32_t bits = (lk & 0x80000000u) ? (lk & 0x7FFFFFFFu) : ~lk;
        float x = __uint_as_float(bits);
        float sc = 1.0f / (1.0f + expf(-x));
        mykey = ((uint64_t)__float_as_uint(sc) << 32) | (uint64_t)(uint32_t)e;
        sel[tid] = mykey;
    }
    __syncthreads();

    // ---- exact rank by (score desc, idx asc): broadcast count, no barriers ----
    if ((uint32_t)tid < n) {
        uint32_t rank = 0;
        for (uint32_t j = 0; j < n; ++j)
            rank += (sel[j] > mykey) ? 1u : 0u;
        if (rank < TOPK) {
            uint32_t idx = 0xFFFFFFFFu - (uint32_t)(mykey & 0xFFFFFFFFull);
            uint32_t lab = idx % NC;
            uint32_t q   = idx / NC;
            float4 bx = reinterpret_cast<const float4*>(pboxes)[(size_t)b * NQ + q];
            float sw = sizes[2 * b + 0];
            float sh = sizes[2 * b + 1];
            float hw = 0.5f * bx.z, hh = 0.5f * bx.w;
            float4 o;
            o.x = (bx.x - hw) * sw;
            o.y = (bx.y - hh) * sh;
            o.z = (bx.x + hw) * sw;
            o.w = (bx.y + hh) * sh;
            out[(size_t)b * TOPK + rank] = (float)lab;                                   // labels
            reinterpret_cast<float4*>(out + (size_t)NBATCH * TOPK)[(size_t)b * TOPK + rank] = o; // boxes
            out[(size_t)NBATCH * TOPK * 5 + (size_t)b * TOPK + rank] =
                __uint_as_float((uint32_t)(mykey >> 32));                                // scores
        }
    }
}

extern "C" void kernel_launch(void* const* d_in, const int* in_sizes, int n_in,
                              void* d_out, int out_size, void* d_ws, size_t ws_size,
                              hipStream_t stream) {
    const float* logits = (const float*)d_in[0];   // [1024,300,80] f32
    const float* pboxes = (const float*)d_in[1];   // [1024,300,4]  f32
    const float* sizes  = (const float*)d_in[2];   // [1024,2]      f32
    float* out = (float*)d_out;                    // labels | boxes | scores (flat f32)

    hipLaunchKernelGGL(rtdetr_post_kernel, dim3(NBATCH), dim3(NT), 0, stream,
                       logits, pboxes, sizes, out);
}